// Round 2
// baseline (1986.298 us; speedup 1.0000x reference)
//
#include <hip/hip_runtime.h>
#include <math.h>

#define BB 8  // batch count (fixed by problem instance)

__device__ __forceinline__ float sigmoidf_(float v) {
    return 1.0f / (1.0f + __expf(-v));
}

// ---- Pass 1: column-wise sum / sumsq of edge_attr (E,2) in double ----
__global__ void ea_reduce_kernel(const float* __restrict__ ea, int E, double* __restrict__ acc) {
    __shared__ double sh[4][256];
    int tid = threadIdx.x;
    double s0 = 0, q0 = 0, s1 = 0, q1 = 0;
    for (int i = blockIdx.x * blockDim.x + tid; i < E; i += gridDim.x * blockDim.x) {
        float a = ea[2 * i];
        float b = ea[2 * i + 1];
        s0 += (double)a; q0 += (double)a * (double)a;
        s1 += (double)b; q1 += (double)b * (double)b;
    }
    sh[0][tid] = s0; sh[1][tid] = q0; sh[2][tid] = s1; sh[3][tid] = q1;
    __syncthreads();
    for (int off = 128; off > 0; off >>= 1) {
        if (tid < off) {
            sh[0][tid] += sh[0][tid + off];
            sh[1][tid] += sh[1][tid + off];
            sh[2][tid] += sh[2][tid + off];
            sh[3][tid] += sh[3][tid + off];
        }
        __syncthreads();
    }
    if (tid == 0) {
        atomicAdd(&acc[0], sh[0][0]);
        atomicAdd(&acc[1], sh[1][0]);
        atomicAdd(&acc[2], sh[2][0]);
        atomicAdd(&acc[3], sh[3][0]);
    }
}

// ---- Pass 2: finalize mean / inv_std (ddof=1) ----
__global__ void finalize_stats_kernel(const double* __restrict__ acc, int E, float* __restrict__ stats) {
    double s0 = acc[0], q0 = acc[1], s1 = acc[2], q1 = acc[3];
    double m0 = s0 / E, m1 = s1 / E;
    double v0 = (q0 - s0 * s0 / E) / (double)(E - 1);
    double v1 = (q1 - s1 * s1 / E) / (double)(E - 1);
    stats[0] = (float)m0;
    stats[1] = (float)(1.0 / sqrt(v0));
    stats[2] = (float)m1;
    stats[3] = (float)(1.0 / sqrt(v1));
}

// ---- Pass 3a: node incidence histogram (each edge touches tgt and src) ----
__global__ void count_kernel(const int* __restrict__ ei, int E, int* __restrict__ cnt) {
    int e = blockIdx.x * blockDim.x + threadIdx.x;
    if (e < E) {
        atomicAdd(&cnt[ei[E + e]], 1);  // tgt (+h)
        atomicAdd(&cnt[ei[e]], 1);      // src (-h)
    }
}

// ---- Pass 3b: exclusive scan over node counts (single block) ----
__global__ __launch_bounds__(1024) void scan_kernel(const int* __restrict__ cnt,
                                                    int* __restrict__ off,
                                                    int* __restrict__ cur, int N) {
    __shared__ int sh[1024];
    int t = threadIdx.x;
    int chunk = (N + 1023) >> 10;
    int lo = t * chunk;
    int hi = lo + chunk; if (hi > N) hi = N;
    int s = 0;
    for (int i = lo; i < hi; i++) s += cnt[i];
    sh[t] = s;
    __syncthreads();
    for (int d = 1; d < 1024; d <<= 1) {
        int v = (t >= d) ? sh[t - d] : 0;
        __syncthreads();
        sh[t] += v;
        __syncthreads();
    }
    int run = (t == 0) ? 0 : sh[t - 1];
    for (int i = lo; i < hi; i++) {
        off[i] = run; cur[i] = run;
        run += cnt[i];
    }
    if (t == 1023) { off[N] = sh[1023]; cur[N] = sh[1023]; }
}

// ---- Pass 3c: fill incidence lists (sign in MSB: set => src side, -h) ----
__global__ void fill_kernel(const int* __restrict__ ei, int E,
                            int* __restrict__ cur, int* __restrict__ list) {
    int e = blockIdx.x * blockDim.x + threadIdx.x;
    if (e < E) {
        int tgt = ei[E + e];
        int src = ei[e];
        int p = atomicAdd(&cur[tgt], 1);
        list[p] = e;
        int q = atomicAdd(&cur[src], 1);
        list[q] = e | 0x80000000;
    }
}

// ---- Pass 4: per-(node,batch) gather — recompute edge MLP, reduce, write once ----
// 16 lanes per (node,batch) pair; 16 pairs per 256-thread block.
__global__ __launch_bounds__(256) void gather_mlp_kernel(
    const float* __restrict__ x, const int* __restrict__ ei,
    const float* __restrict__ ea,
    const float* __restrict__ wmean, const float* __restrict__ wstd,
    const float* __restrict__ W1, const float* __restrict__ b1,
    const float* __restrict__ W2, const float* __restrict__ b2,
    const float* __restrict__ W3, const float* __restrict__ b3,
    const float* __restrict__ stats,
    const int* __restrict__ off, const int* __restrict__ list,
    float* __restrict__ out, int N, int E)
{
    __shared__ float sW1[144], sb1[16], sW2[480], sb2[30], sW3[90];
    int tid = threadIdx.x;
    for (int i = tid; i < 144; i += 256) sW1[i] = W1[i];
    for (int i = tid; i < 480; i += 256) sW2[i] = W2[i];
    if (tid < 16) sb1[tid] = b1[tid];
    if (tid < 30) sb2[tid] = b2[tid];
    if (tid < 90) sW3[tid] = W3[tid];
    __syncthreads();

    int grp = tid >> 4, sub = tid & 15;
    int pair = blockIdx.x * 16 + grp;           // adjacent groups share a node -> L1 reuse
    int node = pair >> 3, batch = pair & 7;     // BB == 8
    if (node >= N) return;

    int o0 = off[node], o1 = off[node + 1];
    float wm0 = wmean[0], wm1 = wmean[1];
    float ws0 = wstd[0],  ws1 = wstd[1];
    float st0 = stats[0], st1 = stats[1], st2 = stats[2], st3 = stats[3];
    const float* xb = x + (size_t)batch * N * 3;

    float a0 = 0.f, a1 = 0.f, a2 = 0.f;
    for (int i = o0 + sub; i < o1; i += 16) {
        int entry = list[i];
        int e = entry & 0x7FFFFFFF;
        float sgn = (entry < 0) ? -1.0f : 1.0f;
        int src = ei[e];
        int tgt = ei[E + e];
        float dist = ea[2 * e];
        float cdir = ea[2 * e + 1];
        float s0 = xb[src * 3 + 0], s1 = xb[src * 3 + 1], s2 = xb[src * 3 + 2];
        float t0 = xb[tgt * 3 + 0], t1 = xb[tgt * 3 + 1], t2 = xb[tgt * 3 + 2];
        float speed = fmaf(s1, ws0, wm0);
        float direc = fmaf(s2, ws1, wm1);
        float theta = fabsf(cdir - direc);
        float ew = fmaxf(0.0f, speed * __cosf(theta) * (3.0f / dist));
        float ea0 = (dist - st0) * st1;
        float ea1 = (cdir - st2) * st3;

        float feat[9] = {s0, s1, s2, t0, t1, t2, ea0, ea1, ew};

        float h1[16];
        #pragma unroll
        for (int j = 0; j < 16; j++) {
            float a = sb1[j];
            #pragma unroll
            for (int k = 0; k < 9; k++) a = fmaf(feat[k], sW1[k * 16 + j], a);
            h1[j] = sigmoidf_(a);
        }

        float g0 = 0.f, g1 = 0.f, g2 = 0.f;
        #pragma unroll
        for (int k = 0; k < 30; k++) {
            float a = sb2[k];
            #pragma unroll
            for (int j = 0; j < 16; j++) a = fmaf(h1[j], sW2[j * 30 + k], a);
            float hk = sigmoidf_(a);
            g0 = fmaf(hk, sW3[k * 3 + 0], g0);
            g1 = fmaf(hk, sW3[k * 3 + 1], g1);
            g2 = fmaf(hk, sW3[k * 3 + 2], g2);
        }
        a0 = fmaf(sgn, g0, a0);
        a1 = fmaf(sgn, g1, a1);
        a2 = fmaf(sgn, g2, a2);
    }

    // reduce across the 16-lane group (xor masks stay within the group)
    #pragma unroll
    for (int m = 8; m >= 1; m >>= 1) {
        a0 += __shfl_xor(a0, m);
        a1 += __shfl_xor(a1, m);
        a2 += __shfl_xor(a2, m);
    }

    if (sub == 0) {
        float* o = out + ((size_t)batch * N + node) * 3;
        o[0] = sigmoidf_(a0 + b3[0]);
        o[1] = sigmoidf_(a1 + b3[1]);
        o[2] = sigmoidf_(a2 + b3[2]);
    }
}

extern "C" void kernel_launch(void* const* d_in, const int* in_sizes, int n_in,
                              void* d_out, int out_size, void* d_ws, size_t ws_size,
                              hipStream_t stream) {
    const float* x     = (const float*)d_in[0];
    const int*   ei    = (const int*)d_in[1];
    const float* ea    = (const float*)d_in[2];
    const float* wmean = (const float*)d_in[3];
    const float* wstd  = (const float*)d_in[4];
    const float* W1    = (const float*)d_in[5];
    const float* b1    = (const float*)d_in[6];
    const float* W2    = (const float*)d_in[7];
    const float* b2    = (const float*)d_in[8];
    const float* W3    = (const float*)d_in[9];
    const float* b3    = (const float*)d_in[10];

    int E = in_sizes[2] / 2;        // edge_attr is (E, 2)
    int N = in_sizes[0] / (BB * 3); // x is (B, N, 3)

    float* out = (float*)d_out;

    char* ws = (char*)d_ws;
    double* acc   = (double*)ws;            // 32 B
    float*  stats = (float*)(ws + 64);      // 16 B
    int*    cnt   = (int*)(ws + 128);       // N
    int*    off   = cnt + N;                // N+1
    int*    cur   = off + N + 1;            // N+1
    int*    list  = cur + N + 1;            // 2E
    // total ws use: 128 + 4*(3N + 2 + 2E) ~= 2.7 MB

    hipMemsetAsync(acc, 0, 64, stream);
    hipMemsetAsync(cnt, 0, sizeof(int) * (size_t)N, stream);

    ea_reduce_kernel<<<256, 256, 0, stream>>>(ea, E, acc);
    finalize_stats_kernel<<<1, 1, 0, stream>>>(acc, E, stats);

    int eblocks = (E + 255) / 256;
    count_kernel<<<eblocks, 256, 0, stream>>>(ei, E, cnt);
    scan_kernel<<<1, 1024, 0, stream>>>(cnt, off, cur, N);
    fill_kernel<<<eblocks, 256, 0, stream>>>(ei, E, cur, list);

    int pairs = N * BB;
    gather_mlp_kernel<<<(pairs + 15) / 16, 256, 0, stream>>>(
        x, ei, ea, wmean, wstd, W1, b1, W2, b2, W3, b3, stats, off, list, out, N, E);
}

// Round 3
// 239.909 us; speedup vs baseline: 8.2794x; 8.2794x over previous
//
#include <hip/hip_runtime.h>
#include <hip/hip_fp16.h>
#include <math.h>

#define BB 8  // batch count (fixed by problem instance)

__device__ __forceinline__ float sigmoidf_(float v) {
    return 1.0f / (1.0f + __expf(-v));
}

// ---- Pass 1: column-wise sum / sumsq of edge_attr (E,2) in double ----
__global__ void ea_reduce_kernel(const float* __restrict__ ea, int E, double* __restrict__ acc) {
    __shared__ double sh[4][256];
    int tid = threadIdx.x;
    double s0 = 0, q0 = 0, s1 = 0, q1 = 0;
    for (int i = blockIdx.x * blockDim.x + tid; i < E; i += gridDim.x * blockDim.x) {
        float a = ea[2 * i];
        float b = ea[2 * i + 1];
        s0 += (double)a; q0 += (double)a * (double)a;
        s1 += (double)b; q1 += (double)b * (double)b;
    }
    sh[0][tid] = s0; sh[1][tid] = q0; sh[2][tid] = s1; sh[3][tid] = q1;
    __syncthreads();
    for (int off = 128; off > 0; off >>= 1) {
        if (tid < off) {
            sh[0][tid] += sh[0][tid + off];
            sh[1][tid] += sh[1][tid + off];
            sh[2][tid] += sh[2][tid + off];
            sh[3][tid] += sh[3][tid + off];
        }
        __syncthreads();
    }
    if (tid == 0) {
        atomicAdd(&acc[0], sh[0][0]);
        atomicAdd(&acc[1], sh[1][0]);
        atomicAdd(&acc[2], sh[2][0]);
        atomicAdd(&acc[3], sh[3][0]);
    }
}

// ---- Pass 2: finalize mean / inv_std (ddof=1) ----
__global__ void finalize_stats_kernel(const double* __restrict__ acc, int E, float* __restrict__ stats) {
    double s0 = acc[0], q0 = acc[1], s1 = acc[2], q1 = acc[3];
    double m0 = s0 / E, m1 = s1 / E;
    double v0 = (q0 - s0 * s0 / E) / (double)(E - 1);
    double v1 = (q1 - s1 * s1 / E) / (double)(E - 1);
    stats[0] = (float)m0;
    stats[1] = (float)(1.0 / sqrt(v0));
    stats[2] = (float)m1;
    stats[3] = (float)(1.0 / sqrt(v1));
}

// ---- CSR build: histogram -> scan -> slot assignment ----
__global__ void count_kernel(const int* __restrict__ ei, int E, int* __restrict__ cnt) {
    int e = blockIdx.x * blockDim.x + threadIdx.x;
    if (e < E) {
        atomicAdd(&cnt[ei[E + e]], 1);  // tgt (+g)
        atomicAdd(&cnt[ei[e]], 1);      // src (-g)
    }
}

__global__ __launch_bounds__(1024) void scan_kernel(const int* __restrict__ cnt,
                                                    int* __restrict__ off,
                                                    int* __restrict__ cur, int N) {
    __shared__ int sh[1024];
    int t = threadIdx.x;
    int chunk = (N + 1023) >> 10;
    int lo = t * chunk;
    int hi = lo + chunk; if (hi > N) hi = N;
    int s = 0;
    for (int i = lo; i < hi; i++) s += cnt[i];
    sh[t] = s;
    __syncthreads();
    for (int d = 1; d < 1024; d <<= 1) {
        int v = (t >= d) ? sh[t - d] : 0;
        __syncthreads();
        sh[t] += v;
        __syncthreads();
    }
    int run = (t == 0) ? 0 : sh[t - 1];
    for (int i = lo; i < hi; i++) {
        off[i] = run; cur[i] = run;
        run += cnt[i];
    }
    if (t == 1023) { off[N] = sh[1023]; cur[N] = sh[1023]; }
}

__global__ void fill_pos_kernel(const int* __restrict__ ei, int E,
                                int* __restrict__ cur,
                                int* __restrict__ pos_t, int* __restrict__ pos_s) {
    int e = blockIdx.x * blockDim.x + threadIdx.x;
    if (e < E) {
        pos_t[e] = atomicAdd(&cur[ei[E + e]], 1);
        pos_s[e] = atomicAdd(&cur[ei[e]], 1);
    }
}

// ---- Phase A: per-(edge,batch) MLP, fused @W3, plain fp16 stores to CSR slots ----
__global__ __launch_bounds__(256) void edge_mlp_store_kernel(
    const float* __restrict__ x, const int* __restrict__ ei,
    const float* __restrict__ ea,
    const float* __restrict__ wmean, const float* __restrict__ wstd,
    const float* __restrict__ W1, const float* __restrict__ b1,
    const float* __restrict__ W2, const float* __restrict__ b2,
    const float* __restrict__ W3,
    const float* __restrict__ stats,
    const int* __restrict__ pos_t, const int* __restrict__ pos_s,
    uint2* __restrict__ gbuf, int N, int E, int S)
{
    __shared__ float sW1[144], sb1[16], sW2[480], sb2[30], sW3[90];
    int tid = threadIdx.x;
    for (int i = tid; i < 144; i += 256) sW1[i] = W1[i];
    for (int i = tid; i < 480; i += 256) sW2[i] = W2[i];
    if (tid < 16) sb1[tid] = b1[tid];
    if (tid < 30) sb2[tid] = b2[tid];
    if (tid < 90) sW3[tid] = W3[tid];
    __syncthreads();

    int idx = blockIdx.x * 256 + tid;
    int e = idx >> 3, b = idx & 7;       // 8 consecutive threads share an edge
    if (e >= E) return;

    int src = ei[e];
    int tgt = ei[E + e];
    float dist = ea[2 * e];
    float cdir = ea[2 * e + 1];
    float ea0 = (dist - stats[0]) * stats[1];
    float ea1 = (cdir - stats[2]) * stats[3];

    const float* xb = x + (size_t)b * N * 3;
    float s0 = xb[src * 3 + 0], s1 = xb[src * 3 + 1], s2 = xb[src * 3 + 2];
    float t0 = xb[tgt * 3 + 0], t1 = xb[tgt * 3 + 1], t2 = xb[tgt * 3 + 2];
    float speed = fmaf(s1, wstd[0], wmean[0]);
    float direc = fmaf(s2, wstd[1], wmean[1]);
    float theta = fabsf(cdir - direc);
    float ew = fmaxf(0.0f, speed * __cosf(theta) * (3.0f / dist));

    float feat[9] = {s0, s1, s2, t0, t1, t2, ea0, ea1, ew};

    float h1[16];
    #pragma unroll
    for (int j = 0; j < 16; j++) {
        float a = sb1[j];
        #pragma unroll
        for (int k = 0; k < 9; k++) a = fmaf(feat[k], sW1[k * 16 + j], a);
        h1[j] = sigmoidf_(a);
    }

    float g0 = 0.f, g1 = 0.f, g2 = 0.f;
    #pragma unroll
    for (int k = 0; k < 30; k++) {
        float a = sb2[k];
        #pragma unroll
        for (int j = 0; j < 16; j++) a = fmaf(h1[j], sW2[j * 30 + k], a);
        float hk = sigmoidf_(a);
        g0 = fmaf(hk, sW3[k * 3 + 0], g0);
        g1 = fmaf(hk, sW3[k * 3 + 1], g1);
        g2 = fmaf(hk, sW3[k * 3 + 2], g2);
    }

    uint2* gb = gbuf + (size_t)b * S;
    __half2 p01 = __floats2half2_rn(g0, g1);
    __half2 p2x = __floats2half2_rn(g2, 0.0f);
    uint2 wp; wp.x = *reinterpret_cast<unsigned int*>(&p01);
              wp.y = *reinterpret_cast<unsigned int*>(&p2x);
    __half2 m01 = __floats2half2_rn(-g0, -g1);
    __half2 m2x = __floats2half2_rn(-g2, 0.0f);
    uint2 wm; wm.x = *reinterpret_cast<unsigned int*>(&m01);
              wm.y = *reinterpret_cast<unsigned int*>(&m2x);
    gb[pos_t[e]] = wp;
    gb[pos_s[e]] = wm;
}

// ---- Phase B: per-(node,batch) coalesced segment sum + bias + sigmoid ----
__global__ __launch_bounds__(256) void segment_sum_kernel(
    const uint2* __restrict__ gbuf, const int* __restrict__ off,
    const float* __restrict__ b3, float* __restrict__ out, int N, int S)
{
    int tid = threadIdx.x;
    int grp = tid >> 4, sub = tid & 15;
    int pair = blockIdx.x * 16 + grp;
    int node = pair >> 3, b = pair & 7;   // BB == 8
    if (node >= N) return;

    int o0 = off[node], o1 = off[node + 1];
    const uint2* gb = gbuf + (size_t)b * S;

    float a0 = 0.f, a1 = 0.f, a2 = 0.f;
    for (int i = o0 + sub; i < o1; i += 16) {
        uint2 w = gb[i];
        __half2 h01 = *reinterpret_cast<__half2*>(&w.x);
        __half2 h2x = *reinterpret_cast<__half2*>(&w.y);
        float2 f01 = __half22float2(h01);
        float2 f2x = __half22float2(h2x);
        a0 += f01.x; a1 += f01.y; a2 += f2x.x;
    }
    #pragma unroll
    for (int m = 8; m >= 1; m >>= 1) {
        a0 += __shfl_xor(a0, m);
        a1 += __shfl_xor(a1, m);
        a2 += __shfl_xor(a2, m);
    }
    if (sub == 0) {
        float* o = out + ((size_t)b * N + node) * 3;
        o[0] = sigmoidf_(a0 + b3[0]);
        o[1] = sigmoidf_(a1 + b3[1]);
        o[2] = sigmoidf_(a2 + b3[2]);
    }
}

// ---- Fallback (small ws): R1 atomic-scatter path ----
__global__ __launch_bounds__(256) void edge_atomic_kernel(
    const float* __restrict__ x, const int* __restrict__ ei,
    const float* __restrict__ ea,
    const float* __restrict__ wmean, const float* __restrict__ wstd,
    const float* __restrict__ W1, const float* __restrict__ b1,
    const float* __restrict__ W2, const float* __restrict__ b2,
    const float* __restrict__ W3,
    const float* __restrict__ stats,
    float* __restrict__ out, int N, int E)
{
    __shared__ float sW1[144], sb1[16], sW2[480], sb2[30], sW3[90];
    int tid = threadIdx.x;
    for (int i = tid; i < 144; i += 256) sW1[i] = W1[i];
    for (int i = tid; i < 480; i += 256) sW2[i] = W2[i];
    if (tid < 16) sb1[tid] = b1[tid];
    if (tid < 30) sb2[tid] = b2[tid];
    if (tid < 90) sW3[tid] = W3[tid];
    __syncthreads();

    int e = blockIdx.x * blockDim.x + tid;
    if (e >= E) return;
    int src = ei[e];
    int tgt = ei[E + e];
    float dist = ea[2 * e];
    float cdir = ea[2 * e + 1];
    float ea0 = (dist - stats[0]) * stats[1];
    float ea1 = (cdir - stats[2]) * stats[3];

    for (int b = 0; b < BB; b++) {
        const float* xb = x + (size_t)b * N * 3;
        float s0 = xb[src * 3 + 0], s1 = xb[src * 3 + 1], s2 = xb[src * 3 + 2];
        float t0 = xb[tgt * 3 + 0], t1 = xb[tgt * 3 + 1], t2 = xb[tgt * 3 + 2];
        float speed = fmaf(s1, wstd[0], wmean[0]);
        float direc = fmaf(s2, wstd[1], wmean[1]);
        float theta = fabsf(cdir - direc);
        float ew = fmaxf(0.0f, speed * __cosf(theta) * (3.0f / dist));
        float feat[9] = {s0, s1, s2, t0, t1, t2, ea0, ea1, ew};
        float h1[16];
        #pragma unroll
        for (int j = 0; j < 16; j++) {
            float a = sb1[j];
            #pragma unroll
            for (int k = 0; k < 9; k++) a = fmaf(feat[k], sW1[k * 16 + j], a);
            h1[j] = sigmoidf_(a);
        }
        float g0 = 0.f, g1 = 0.f, g2 = 0.f;
        #pragma unroll
        for (int k = 0; k < 30; k++) {
            float a = sb2[k];
            #pragma unroll
            for (int j = 0; j < 16; j++) a = fmaf(h1[j], sW2[j * 30 + k], a);
            float hk = sigmoidf_(a);
            g0 = fmaf(hk, sW3[k * 3 + 0], g0);
            g1 = fmaf(hk, sW3[k * 3 + 1], g1);
            g2 = fmaf(hk, sW3[k * 3 + 2], g2);
        }
        float* ot = out + ((size_t)b * N + tgt) * 3;
        float* os = out + ((size_t)b * N + src) * 3;
        atomicAdd(&ot[0], g0);  atomicAdd(&ot[1], g1);  atomicAdd(&ot[2], g2);
        atomicAdd(&os[0], -g0); atomicAdd(&os[1], -g1); atomicAdd(&os[2], -g2);
    }
}

__global__ void output_kernel(float* __restrict__ out, const float* __restrict__ b3, int total) {
    int i = blockIdx.x * blockDim.x + threadIdx.x;
    if (i < total) out[i] = sigmoidf_(out[i] + b3[i % 3]);
}

extern "C" void kernel_launch(void* const* d_in, const int* in_sizes, int n_in,
                              void* d_out, int out_size, void* d_ws, size_t ws_size,
                              hipStream_t stream) {
    const float* x     = (const float*)d_in[0];
    const int*   ei    = (const int*)d_in[1];
    const float* ea    = (const float*)d_in[2];
    const float* wmean = (const float*)d_in[3];
    const float* wstd  = (const float*)d_in[4];
    const float* W1    = (const float*)d_in[5];
    const float* b1    = (const float*)d_in[6];
    const float* W2    = (const float*)d_in[7];
    const float* b2    = (const float*)d_in[8];
    const float* W3    = (const float*)d_in[9];
    const float* b3    = (const float*)d_in[10];

    int E = in_sizes[2] / 2;        // edge_attr is (E, 2)
    int N = in_sizes[0] / (BB * 3); // x is (B, N, 3)
    int S = 2 * E;                  // slots per batch

    float* out = (float*)d_out;
    char* ws = (char*)d_ws;
    double* acc   = (double*)ws;                 // 32 B @ 0
    float*  stats = (float*)(ws + 64);           // 16 B
    int*    cnt   = (int*)(ws + 128);            // N
    int*    off   = cnt + N;                     // N+1
    int*    cur   = off + N + 1;                 // N+1
    int*    pos_t = cur + N + 1;                 // E
    int*    pos_s = pos_t + E;                   // E

    size_t head = 128 + sizeof(int) * ((size_t)3 * N + 2 + 2 * (size_t)E);
    head = (head + 255) & ~(size_t)255;
    uint2* gbuf = (uint2*)(ws + head);
    size_t needed = head + (size_t)S * BB * sizeof(uint2);

    hipMemsetAsync(acc, 0, 64, stream);
    ea_reduce_kernel<<<256, 256, 0, stream>>>(ea, E, acc);
    finalize_stats_kernel<<<1, 1, 0, stream>>>(acc, E, stats);

    int eblocks = (E + 255) / 256;

    if (needed <= ws_size) {
        hipMemsetAsync(cnt, 0, sizeof(int) * (size_t)N, stream);
        count_kernel<<<eblocks, 256, 0, stream>>>(ei, E, cnt);
        scan_kernel<<<1, 1024, 0, stream>>>(cnt, off, cur, N);
        fill_pos_kernel<<<eblocks, 256, 0, stream>>>(ei, E, cur, pos_t, pos_s);

        int ebB = ((E * BB) + 255) / 256;
        edge_mlp_store_kernel<<<ebB, 256, 0, stream>>>(
            x, ei, ea, wmean, wstd, W1, b1, W2, b2, W3, stats,
            pos_t, pos_s, gbuf, N, E, S);

        int pairs = N * BB;
        segment_sum_kernel<<<(pairs + 15) / 16, 256, 0, stream>>>(
            gbuf, off, b3, out, N, S);
    } else {
        hipMemsetAsync(d_out, 0, (size_t)out_size * sizeof(float), stream);
        edge_atomic_kernel<<<eblocks, 256, 0, stream>>>(
            x, ei, ea, wmean, wstd, W1, b1, W2, b2, W3, stats, out, N, E);
        output_kernel<<<(out_size + 255) / 256, 256, 0, stream>>>(out, b3, out_size);
    }
}

// Round 4
// 218.064 us; speedup vs baseline: 9.1088x; 1.1002x over previous
//
#include <hip/hip_runtime.h>
#include <hip/hip_fp16.h>
#include <math.h>

#define BB 8  // batch count (fixed by problem instance)

__device__ __forceinline__ float sigmoidf_(float v) {
    return 1.0f / (1.0f + __expf(-v));
}

// ---- Pass 1: column-wise sum / sumsq of edge_attr (E,2) in double ----
__global__ void ea_reduce_kernel(const float* __restrict__ ea, int E, double* __restrict__ acc) {
    __shared__ double sh[4][256];
    int tid = threadIdx.x;
    double s0 = 0, q0 = 0, s1 = 0, q1 = 0;
    for (int i = blockIdx.x * blockDim.x + tid; i < E; i += gridDim.x * blockDim.x) {
        float a = ea[2 * i];
        float b = ea[2 * i + 1];
        s0 += (double)a; q0 += (double)a * (double)a;
        s1 += (double)b; q1 += (double)b * (double)b;
    }
    sh[0][tid] = s0; sh[1][tid] = q0; sh[2][tid] = s1; sh[3][tid] = q1;
    __syncthreads();
    for (int off = 128; off > 0; off >>= 1) {
        if (tid < off) {
            sh[0][tid] += sh[0][tid + off];
            sh[1][tid] += sh[1][tid + off];
            sh[2][tid] += sh[2][tid + off];
            sh[3][tid] += sh[3][tid + off];
        }
        __syncthreads();
    }
    if (tid == 0) {
        atomicAdd(&acc[0], sh[0][0]);
        atomicAdd(&acc[1], sh[1][0]);
        atomicAdd(&acc[2], sh[2][0]);
        atomicAdd(&acc[3], sh[3][0]);
    }
}

// ---- Pass 2: finalize mean / inv_std (ddof=1) ----
__global__ void finalize_stats_kernel(const double* __restrict__ acc, int E, float* __restrict__ stats) {
    double s0 = acc[0], q0 = acc[1], s1 = acc[2], q1 = acc[3];
    double m0 = s0 / E, m1 = s1 / E;
    double v0 = (q0 - s0 * s0 / E) / (double)(E - 1);
    double v1 = (q1 - s1 * s1 / E) / (double)(E - 1);
    stats[0] = (float)m0;
    stats[1] = (float)(1.0 / sqrt(v0));
    stats[2] = (float)m1;
    stats[3] = (float)(1.0 / sqrt(v1));
}

// ---- CSR build: histogram -> scan -> slot assignment ----
__global__ void count_kernel(const int* __restrict__ ei, int E, int* __restrict__ cnt) {
    int e = blockIdx.x * blockDim.x + threadIdx.x;
    if (e < E) {
        atomicAdd(&cnt[ei[E + e]], 1);  // tgt (+g)
        atomicAdd(&cnt[ei[e]], 1);      // src (-g)
    }
}

__global__ __launch_bounds__(1024) void scan_kernel(const int* __restrict__ cnt,
                                                    int* __restrict__ off,
                                                    int* __restrict__ cur, int N) {
    __shared__ int sh[1024];
    int t = threadIdx.x;
    int chunk = (N + 1023) >> 10;
    int lo = t * chunk;
    int hi = lo + chunk; if (hi > N) hi = N;
    int s = 0;
    for (int i = lo; i < hi; i++) s += cnt[i];
    sh[t] = s;
    __syncthreads();
    for (int d = 1; d < 1024; d <<= 1) {
        int v = (t >= d) ? sh[t - d] : 0;
        __syncthreads();
        sh[t] += v;
        __syncthreads();
    }
    int run = (t == 0) ? 0 : sh[t - 1];
    for (int i = lo; i < hi; i++) {
        off[i] = run; cur[i] = run;
        run += cnt[i];
    }
    if (t == 1023) { off[N] = sh[1023]; cur[N] = sh[1023]; }
}

__global__ void fill_pos_kernel(const int* __restrict__ ei, int E,
                                int* __restrict__ cur,
                                int* __restrict__ pos_t, int* __restrict__ pos_s) {
    int e = blockIdx.x * blockDim.x + threadIdx.x;
    if (e < E) {
        pos_t[e] = atomicAdd(&cur[ei[E + e]], 1);
        pos_s[e] = atomicAdd(&cur[ei[e]], 1);
    }
}

// ---- the 9->16->30->(@W3) MLP, weights read as wave-uniform scalar loads ----
__device__ __forceinline__ void mlp_eval(
    const float feat[9],
    const float* __restrict__ W1, const float* __restrict__ b1,
    const float* __restrict__ W2, const float* __restrict__ b2,
    const float* __restrict__ W3,
    float& g0, float& g1, float& g2)
{
    float acc1[16];
    #pragma unroll
    for (int j = 0; j < 16; j++) acc1[j] = b1[j];
    #pragma unroll
    for (int k = 0; k < 9; k++) {
        float fk = feat[k];
        #pragma unroll
        for (int j = 0; j < 16; j++) acc1[j] = fmaf(fk, W1[k * 16 + j], acc1[j]);
    }

    float acc2[30];
    #pragma unroll
    for (int k = 0; k < 30; k++) acc2[k] = b2[k];
    #pragma unroll
    for (int j = 0; j < 16; j++) {
        float hj = sigmoidf_(acc1[j]);
        #pragma unroll
        for (int k = 0; k < 30; k++) acc2[k] = fmaf(hj, W2[j * 30 + k], acc2[k]);
    }

    g0 = 0.f; g1 = 0.f; g2 = 0.f;
    #pragma unroll
    for (int k = 0; k < 30; k++) {
        float hk = sigmoidf_(acc2[k]);
        g0 = fmaf(hk, W3[k * 3 + 0], g0);
        g1 = fmaf(hk, W3[k * 3 + 1], g1);
        g2 = fmaf(hk, W3[k * 3 + 2], g2);
    }
}

// ---- Phase A: per-(edge,batch) MLP, fused @W3, plain fp16 stores to CSR slots ----
// grid = (ceil(E/256), BB): lanes cover consecutive edges -> coalesced metadata loads
__global__ __launch_bounds__(256) void edge_mlp_store_kernel(
    const float* __restrict__ x, const int* __restrict__ ei,
    const float* __restrict__ ea,
    const float* __restrict__ wmean, const float* __restrict__ wstd,
    const float* __restrict__ W1, const float* __restrict__ b1,
    const float* __restrict__ W2, const float* __restrict__ b2,
    const float* __restrict__ W3,
    const float* __restrict__ stats,
    const int* __restrict__ pos_t, const int* __restrict__ pos_s,
    uint2* __restrict__ gbuf, int N, int E, int S)
{
    int e = blockIdx.x * 256 + threadIdx.x;
    int b = blockIdx.y;
    if (e >= E) return;

    int src = ei[e];
    int tgt = ei[E + e];
    float dist = ea[2 * e];
    float cdir = ea[2 * e + 1];
    float ea0 = (dist - stats[0]) * stats[1];
    float ea1 = (cdir - stats[2]) * stats[3];

    const float* xb = x + (size_t)b * N * 3;
    float s0 = xb[src * 3 + 0], s1 = xb[src * 3 + 1], s2 = xb[src * 3 + 2];
    float t0 = xb[tgt * 3 + 0], t1 = xb[tgt * 3 + 1], t2 = xb[tgt * 3 + 2];
    float speed = fmaf(s1, wstd[0], wmean[0]);
    float direc = fmaf(s2, wstd[1], wmean[1]);
    float theta = fabsf(cdir - direc);
    float ew = fmaxf(0.0f, speed * __cosf(theta) * (3.0f / dist));

    float feat[9] = {s0, s1, s2, t0, t1, t2, ea0, ea1, ew};
    float g0, g1, g2;
    mlp_eval(feat, W1, b1, W2, b2, W3, g0, g1, g2);

    uint2* gb = gbuf + (size_t)b * S;
    __half2 p01 = __floats2half2_rn(g0, g1);
    __half2 p2x = __floats2half2_rn(g2, 0.0f);
    uint2 wp; wp.x = *reinterpret_cast<unsigned int*>(&p01);
              wp.y = *reinterpret_cast<unsigned int*>(&p2x);
    __half2 m01 = __floats2half2_rn(-g0, -g1);
    __half2 m2x = __floats2half2_rn(-g2, 0.0f);
    uint2 wm; wm.x = *reinterpret_cast<unsigned int*>(&m01);
              wm.y = *reinterpret_cast<unsigned int*>(&m2x);
    gb[pos_t[e]] = wp;
    gb[pos_s[e]] = wm;
}

// ---- Phase B: per-(node,batch) coalesced segment sum + bias + sigmoid ----
__global__ __launch_bounds__(256) void segment_sum_kernel(
    const uint2* __restrict__ gbuf, const int* __restrict__ off,
    const float* __restrict__ b3, float* __restrict__ out, int N, int S)
{
    int tid = threadIdx.x;
    int grp = tid >> 4, sub = tid & 15;
    int pair = blockIdx.x * 16 + grp;
    int node = pair >> 3, b = pair & 7;   // BB == 8
    if (node >= N) return;

    int o0 = off[node], o1 = off[node + 1];
    const uint2* gb = gbuf + (size_t)b * S;

    float a0 = 0.f, a1 = 0.f, a2 = 0.f;
    for (int i = o0 + sub; i < o1; i += 16) {
        uint2 w = gb[i];
        __half2 h01 = *reinterpret_cast<__half2*>(&w.x);
        __half2 h2x = *reinterpret_cast<__half2*>(&w.y);
        float2 f01 = __half22float2(h01);
        float2 f2x = __half22float2(h2x);
        a0 += f01.x; a1 += f01.y; a2 += f2x.x;
    }
    #pragma unroll
    for (int m = 8; m >= 1; m >>= 1) {
        a0 += __shfl_xor(a0, m);
        a1 += __shfl_xor(a1, m);
        a2 += __shfl_xor(a2, m);
    }
    if (sub == 0) {
        float* o = out + ((size_t)b * N + node) * 3;
        o[0] = sigmoidf_(a0 + b3[0]);
        o[1] = sigmoidf_(a1 + b3[1]);
        o[2] = sigmoidf_(a2 + b3[2]);
    }
}

// ---- Fallback (small ws): atomic-scatter path ----
__global__ __launch_bounds__(256) void edge_atomic_kernel(
    const float* __restrict__ x, const int* __restrict__ ei,
    const float* __restrict__ ea,
    const float* __restrict__ wmean, const float* __restrict__ wstd,
    const float* __restrict__ W1, const float* __restrict__ b1,
    const float* __restrict__ W2, const float* __restrict__ b2,
    const float* __restrict__ W3,
    const float* __restrict__ stats,
    float* __restrict__ out, int N, int E)
{
    int e = blockIdx.x * blockDim.x + threadIdx.x;
    if (e >= E) return;
    int src = ei[e];
    int tgt = ei[E + e];
    float dist = ea[2 * e];
    float cdir = ea[2 * e + 1];
    float ea0 = (dist - stats[0]) * stats[1];
    float ea1 = (cdir - stats[2]) * stats[3];

    for (int b = 0; b < BB; b++) {
        const float* xb = x + (size_t)b * N * 3;
        float s0 = xb[src * 3 + 0], s1 = xb[src * 3 + 1], s2 = xb[src * 3 + 2];
        float t0 = xb[tgt * 3 + 0], t1 = xb[tgt * 3 + 1], t2 = xb[tgt * 3 + 2];
        float speed = fmaf(s1, wstd[0], wmean[0]);
        float direc = fmaf(s2, wstd[1], wmean[1]);
        float theta = fabsf(cdir - direc);
        float ew = fmaxf(0.0f, speed * __cosf(theta) * (3.0f / dist));
        float feat[9] = {s0, s1, s2, t0, t1, t2, ea0, ea1, ew};
        float g0, g1, g2;
        mlp_eval(feat, W1, b1, W2, b2, W3, g0, g1, g2);
        float* ot = out + ((size_t)b * N + tgt) * 3;
        float* os = out + ((size_t)b * N + src) * 3;
        atomicAdd(&ot[0], g0);  atomicAdd(&ot[1], g1);  atomicAdd(&ot[2], g2);
        atomicAdd(&os[0], -g0); atomicAdd(&os[1], -g1); atomicAdd(&os[2], -g2);
    }
}

__global__ void output_kernel(float* __restrict__ out, const float* __restrict__ b3, int total) {
    int i = blockIdx.x * blockDim.x + threadIdx.x;
    if (i < total) out[i] = sigmoidf_(out[i] + b3[i % 3]);
}

extern "C" void kernel_launch(void* const* d_in, const int* in_sizes, int n_in,
                              void* d_out, int out_size, void* d_ws, size_t ws_size,
                              hipStream_t stream) {
    const float* x     = (const float*)d_in[0];
    const int*   ei    = (const int*)d_in[1];
    const float* ea    = (const float*)d_in[2];
    const float* wmean = (const float*)d_in[3];
    const float* wstd  = (const float*)d_in[4];
    const float* W1    = (const float*)d_in[5];
    const float* b1    = (const float*)d_in[6];
    const float* W2    = (const float*)d_in[7];
    const float* b2    = (const float*)d_in[8];
    const float* W3    = (const float*)d_in[9];
    const float* b3    = (const float*)d_in[10];

    int E = in_sizes[2] / 2;        // edge_attr is (E, 2)
    int N = in_sizes[0] / (BB * 3); // x is (B, N, 3)
    int S = 2 * E;                  // slots per batch

    float* out = (float*)d_out;
    char* ws = (char*)d_ws;
    double* acc   = (double*)ws;                 // 32 B @ 0
    float*  stats = (float*)(ws + 64);           // 16 B
    int*    cnt   = (int*)(ws + 128);            // N
    int*    off   = cnt + N;                     // N+1
    int*    cur   = off + N + 1;                 // N+1
    int*    pos_t = cur + N + 1;                 // E
    int*    pos_s = pos_t + E;                   // E

    size_t head = 128 + sizeof(int) * ((size_t)3 * N + 2 + 2 * (size_t)E);
    head = (head + 255) & ~(size_t)255;
    uint2* gbuf = (uint2*)(ws + head);
    size_t needed = head + (size_t)S * BB * sizeof(uint2);

    hipMemsetAsync(acc, 0, 64, stream);
    ea_reduce_kernel<<<256, 256, 0, stream>>>(ea, E, acc);
    finalize_stats_kernel<<<1, 1, 0, stream>>>(acc, E, stats);

    int eblocks = (E + 255) / 256;

    if (needed <= ws_size) {
        hipMemsetAsync(cnt, 0, sizeof(int) * (size_t)N, stream);
        count_kernel<<<eblocks, 256, 0, stream>>>(ei, E, cnt);
        scan_kernel<<<1, 1024, 0, stream>>>(cnt, off, cur, N);
        fill_pos_kernel<<<eblocks, 256, 0, stream>>>(ei, E, cur, pos_t, pos_s);

        dim3 gridA(eblocks, BB);
        edge_mlp_store_kernel<<<gridA, 256, 0, stream>>>(
            x, ei, ea, wmean, wstd, W1, b1, W2, b2, W3, stats,
            pos_t, pos_s, gbuf, N, E, S);

        int pairs = N * BB;
        segment_sum_kernel<<<(pairs + 15) / 16, 256, 0, stream>>>(
            gbuf, off, b3, out, N, S);
    } else {
        hipMemsetAsync(d_out, 0, (size_t)out_size * sizeof(float), stream);
        edge_atomic_kernel<<<eblocks, 256, 0, stream>>>(
            x, ei, ea, wmean, wstd, W1, b1, W2, b2, W3, stats, out, N, E);
        output_kernel<<<(out_size + 255) / 256, 256, 0, stream>>>(out, b3, out_size);
    }
}

// Round 5
// 184.165 us; speedup vs baseline: 10.7854x; 1.1841x over previous
//
#include <hip/hip_runtime.h>
#include <hip/hip_fp16.h>
#include <math.h>

#define BB 8  // batch count (fixed by problem instance)

typedef float f32x2 __attribute__((ext_vector_type(2)));

__device__ __forceinline__ float sigmoidf_(float v) {
    // raw v_rcp_f32 (~1 ULP) instead of IEEE division (div_scale/fmas/fixup chain)
    return __builtin_amdgcn_rcpf(1.0f + __expf(-v));
}

// ---- Pass 1 (fused): edge_attr stats partials + node incidence histogram ----
__global__ void stats_count_kernel(const float* __restrict__ ea, const int* __restrict__ ei,
                                   int E, double* __restrict__ acc, int* __restrict__ cnt) {
    __shared__ double sh[4][256];
    int tid = threadIdx.x;
    double s0 = 0, q0 = 0, s1 = 0, q1 = 0;
    for (int i = blockIdx.x * blockDim.x + tid; i < E; i += gridDim.x * blockDim.x) {
        float a = ea[2 * i];
        float b = ea[2 * i + 1];
        s0 += (double)a; q0 += (double)a * (double)a;
        s1 += (double)b; q1 += (double)b * (double)b;
        atomicAdd(&cnt[ei[E + i]], 1);  // tgt (+g)
        atomicAdd(&cnt[ei[i]], 1);      // src (-g)
    }
    sh[0][tid] = s0; sh[1][tid] = q0; sh[2][tid] = s1; sh[3][tid] = q1;
    __syncthreads();
    for (int off = 128; off > 0; off >>= 1) {
        if (tid < off) {
            sh[0][tid] += sh[0][tid + off];
            sh[1][tid] += sh[1][tid + off];
            sh[2][tid] += sh[2][tid + off];
            sh[3][tid] += sh[3][tid + off];
        }
        __syncthreads();
    }
    if (tid == 0) {
        atomicAdd(&acc[0], sh[0][0]);
        atomicAdd(&acc[1], sh[1][0]);
        atomicAdd(&acc[2], sh[2][0]);
        atomicAdd(&acc[3], sh[3][0]);
    }
}

// ---- Pass 2 (fused): exclusive scan over node counts + stats finalize ----
__global__ __launch_bounds__(1024) void scan_kernel(const int* __restrict__ cnt,
                                                    int* __restrict__ off,
                                                    int* __restrict__ cur, int N,
                                                    const double* __restrict__ acc, int E,
                                                    float* __restrict__ stats) {
    if (threadIdx.x == 0) {
        double s0 = acc[0], q0 = acc[1], s1 = acc[2], q1 = acc[3];
        double v0 = (q0 - s0 * s0 / E) / (double)(E - 1);
        double v1 = (q1 - s1 * s1 / E) / (double)(E - 1);
        stats[0] = (float)(s0 / E);
        stats[1] = (float)(1.0 / sqrt(v0));
        stats[2] = (float)(s1 / E);
        stats[3] = (float)(1.0 / sqrt(v1));
    }
    __shared__ int sh[1024];
    int t = threadIdx.x;
    int chunk = (N + 1023) >> 10;
    int lo = t * chunk;
    int hi = lo + chunk; if (hi > N) hi = N;
    int s = 0;
    for (int i = lo; i < hi; i++) s += cnt[i];
    sh[t] = s;
    __syncthreads();
    for (int d = 1; d < 1024; d <<= 1) {
        int v = (t >= d) ? sh[t - d] : 0;
        __syncthreads();
        sh[t] += v;
        __syncthreads();
    }
    int run = (t == 0) ? 0 : sh[t - 1];
    for (int i = lo; i < hi; i++) {
        off[i] = run; cur[i] = run;
        run += cnt[i];
    }
    if (t == 1023) { off[N] = sh[1023]; cur[N] = sh[1023]; }
}

__global__ void fill_pos_kernel(const int* __restrict__ ei, int E,
                                int* __restrict__ cur,
                                int* __restrict__ pos_t, int* __restrict__ pos_s) {
    int e = blockIdx.x * blockDim.x + threadIdx.x;
    if (e < E) {
        pos_t[e] = atomicAdd(&cur[ei[E + e]], 1);
        pos_s[e] = atomicAdd(&cur[ei[e]], 1);
    }
}

// ---- the 9->16->30->(@W3) MLP: packed fp32 FMA, scalar weight loads ----
__device__ __forceinline__ void mlp_eval(
    const float feat[9],
    const float* __restrict__ W1, const float* __restrict__ b1,
    const float* __restrict__ W2, const float* __restrict__ b2,
    const float* __restrict__ W3,
    float& g0, float& g1, float& g2)
{
    const f32x2* W1p = (const f32x2*)W1;   // [9][8] pairs along j
    const f32x2* b1p = (const f32x2*)b1;
    f32x2 acc1[8];
    #pragma unroll
    for (int j = 0; j < 8; j++) acc1[j] = b1p[j];
    #pragma unroll
    for (int k = 0; k < 9; k++) {
        f32x2 fk2 = {feat[k], feat[k]};
        #pragma unroll
        for (int j = 0; j < 8; j++)
            acc1[j] = __builtin_elementwise_fma(fk2, W1p[k * 8 + j], acc1[j]);
    }
    float h1[16];
    #pragma unroll
    for (int j = 0; j < 8; j++) {
        h1[2 * j]     = sigmoidf_(acc1[j].x);
        h1[2 * j + 1] = sigmoidf_(acc1[j].y);
    }

    const f32x2* W2p = (const f32x2*)W2;   // [16][15] pairs along k
    const f32x2* b2p = (const f32x2*)b2;
    f32x2 acc2[15];
    #pragma unroll
    for (int k = 0; k < 15; k++) acc2[k] = b2p[k];
    #pragma unroll
    for (int j = 0; j < 16; j++) {
        f32x2 hj2 = {h1[j], h1[j]};
        #pragma unroll
        for (int k = 0; k < 15; k++)
            acc2[k] = __builtin_elementwise_fma(hj2, W2p[j * 15 + k], acc2[k]);
    }

    g0 = 0.f; g1 = 0.f; g2 = 0.f;
    #pragma unroll
    for (int k = 0; k < 15; k++) {
        float ha = sigmoidf_(acc2[k].x);
        float hb = sigmoidf_(acc2[k].y);
        int ka = 2 * k, kb = 2 * k + 1;
        g0 = fmaf(ha, W3[ka * 3 + 0], g0); g0 = fmaf(hb, W3[kb * 3 + 0], g0);
        g1 = fmaf(ha, W3[ka * 3 + 1], g1); g1 = fmaf(hb, W3[kb * 3 + 1], g1);
        g2 = fmaf(ha, W3[ka * 3 + 2], g2); g2 = fmaf(hb, W3[kb * 3 + 2], g2);
    }
}

// ---- Phase A: per-(edge,batch) MLP, fused @W3, plain fp16 stores to CSR slots ----
__global__ __launch_bounds__(256) void edge_mlp_store_kernel(
    const float* __restrict__ x, const int* __restrict__ ei,
    const float* __restrict__ ea,
    const float* __restrict__ wmean, const float* __restrict__ wstd,
    const float* __restrict__ W1, const float* __restrict__ b1,
    const float* __restrict__ W2, const float* __restrict__ b2,
    const float* __restrict__ W3,
    const float* __restrict__ stats,
    const int* __restrict__ pos_t, const int* __restrict__ pos_s,
    uint2* __restrict__ gbuf, int N, int E, int S)
{
    int e = blockIdx.x * 256 + threadIdx.x;
    int b = blockIdx.y;
    if (e >= E) return;

    int src = ei[e];
    int tgt = ei[E + e];
    float dist = ea[2 * e];
    float cdir = ea[2 * e + 1];
    float ea0 = (dist - stats[0]) * stats[1];
    float ea1 = (cdir - stats[2]) * stats[3];

    const float* xb = x + (size_t)b * N * 3;
    float s0 = xb[src * 3 + 0], s1 = xb[src * 3 + 1], s2 = xb[src * 3 + 2];
    float t0 = xb[tgt * 3 + 0], t1 = xb[tgt * 3 + 1], t2 = xb[tgt * 3 + 2];
    float speed = fmaf(s1, wstd[0], wmean[0]);
    float direc = fmaf(s2, wstd[1], wmean[1]);
    float theta = fabsf(cdir - direc);
    float ew = fmaxf(0.0f, speed * __cosf(theta) * 3.0f * __builtin_amdgcn_rcpf(dist));

    float feat[9] = {s0, s1, s2, t0, t1, t2, ea0, ea1, ew};
    float g0, g1, g2;
    mlp_eval(feat, W1, b1, W2, b2, W3, g0, g1, g2);

    uint2* gb = gbuf + (size_t)b * S;
    __half2 p01 = __floats2half2_rn(g0, g1);
    __half2 p2x = __floats2half2_rn(g2, 0.0f);
    uint2 wp; wp.x = *reinterpret_cast<unsigned int*>(&p01);
              wp.y = *reinterpret_cast<unsigned int*>(&p2x);
    __half2 m01 = __floats2half2_rn(-g0, -g1);
    __half2 m2x = __floats2half2_rn(-g2, 0.0f);
    uint2 wm; wm.x = *reinterpret_cast<unsigned int*>(&m01);
              wm.y = *reinterpret_cast<unsigned int*>(&m2x);
    gb[pos_t[e]] = wp;
    gb[pos_s[e]] = wm;
}

// ---- Phase B: per-(node,batch) coalesced segment sum + bias + sigmoid ----
__global__ __launch_bounds__(256) void segment_sum_kernel(
    const uint2* __restrict__ gbuf, const int* __restrict__ off,
    const float* __restrict__ b3, float* __restrict__ out, int N, int S)
{
    int tid = threadIdx.x;
    int grp = tid >> 4, sub = tid & 15;
    int pair = blockIdx.x * 16 + grp;
    int node = pair >> 3, b = pair & 7;   // BB == 8
    if (node >= N) return;

    int o0 = off[node], o1 = off[node + 1];
    const uint2* gb = gbuf + (size_t)b * S;

    float a0 = 0.f, a1 = 0.f, a2 = 0.f;
    for (int i = o0 + sub; i < o1; i += 16) {
        uint2 w = gb[i];
        __half2 h01 = *reinterpret_cast<__half2*>(&w.x);
        __half2 h2x = *reinterpret_cast<__half2*>(&w.y);
        float2 f01 = __half22float2(h01);
        float2 f2x = __half22float2(h2x);
        a0 += f01.x; a1 += f01.y; a2 += f2x.x;
    }
    #pragma unroll
    for (int m = 8; m >= 1; m >>= 1) {
        a0 += __shfl_xor(a0, m);
        a1 += __shfl_xor(a1, m);
        a2 += __shfl_xor(a2, m);
    }
    if (sub == 0) {
        float* o = out + ((size_t)b * N + node) * 3;
        o[0] = sigmoidf_(a0 + b3[0]);
        o[1] = sigmoidf_(a1 + b3[1]);
        o[2] = sigmoidf_(a2 + b3[2]);
    }
}

// ---- Fallback (small ws): atomic-scatter path ----
__global__ __launch_bounds__(256) void edge_atomic_kernel(
    const float* __restrict__ x, const int* __restrict__ ei,
    const float* __restrict__ ea,
    const float* __restrict__ wmean, const float* __restrict__ wstd,
    const float* __restrict__ W1, const float* __restrict__ b1,
    const float* __restrict__ W2, const float* __restrict__ b2,
    const float* __restrict__ W3,
    const float* __restrict__ stats,
    float* __restrict__ out, int N, int E)
{
    int e = blockIdx.x * blockDim.x + threadIdx.x;
    if (e >= E) return;
    int src = ei[e];
    int tgt = ei[E + e];
    float dist = ea[2 * e];
    float cdir = ea[2 * e + 1];
    float ea0 = (dist - stats[0]) * stats[1];
    float ea1 = (cdir - stats[2]) * stats[3];

    for (int b = 0; b < BB; b++) {
        const float* xb = x + (size_t)b * N * 3;
        float s0 = xb[src * 3 + 0], s1 = xb[src * 3 + 1], s2 = xb[src * 3 + 2];
        float t0 = xb[tgt * 3 + 0], t1 = xb[tgt * 3 + 1], t2 = xb[tgt * 3 + 2];
        float speed = fmaf(s1, wstd[0], wmean[0]);
        float direc = fmaf(s2, wstd[1], wmean[1]);
        float theta = fabsf(cdir - direc);
        float ew = fmaxf(0.0f, speed * __cosf(theta) * 3.0f * __builtin_amdgcn_rcpf(dist));
        float feat[9] = {s0, s1, s2, t0, t1, t2, ea0, ea1, ew};
        float g0, g1, g2;
        mlp_eval(feat, W1, b1, W2, b2, W3, g0, g1, g2);
        float* ot = out + ((size_t)b * N + tgt) * 3;
        float* os = out + ((size_t)b * N + src) * 3;
        atomicAdd(&ot[0], g0);  atomicAdd(&ot[1], g1);  atomicAdd(&ot[2], g2);
        atomicAdd(&os[0], -g0); atomicAdd(&os[1], -g1); atomicAdd(&os[2], -g2);
    }
}

__global__ void output_kernel(float* __restrict__ out, const float* __restrict__ b3, int total) {
    int i = blockIdx.x * blockDim.x + threadIdx.x;
    if (i < total) out[i] = sigmoidf_(out[i] + b3[i % 3]);
}

extern "C" void kernel_launch(void* const* d_in, const int* in_sizes, int n_in,
                              void* d_out, int out_size, void* d_ws, size_t ws_size,
                              hipStream_t stream) {
    const float* x     = (const float*)d_in[0];
    const int*   ei    = (const int*)d_in[1];
    const float* ea    = (const float*)d_in[2];
    const float* wmean = (const float*)d_in[3];
    const float* wstd  = (const float*)d_in[4];
    const float* W1    = (const float*)d_in[5];
    const float* b1    = (const float*)d_in[6];
    const float* W2    = (const float*)d_in[7];
    const float* b2    = (const float*)d_in[8];
    const float* W3    = (const float*)d_in[9];
    const float* b3    = (const float*)d_in[10];

    int E = in_sizes[2] / 2;        // edge_attr is (E, 2)
    int N = in_sizes[0] / (BB * 3); // x is (B, N, 3)
    int S = 2 * E;                  // slots per batch

    float* out = (float*)d_out;
    char* ws = (char*)d_ws;

    // layout: [cnt N ints][acc 4 doubles][stats 4 floats][off N+1][cur N+1][pos_t E][pos_s E][gbuf]
    size_t cntBytes = (((size_t)N * 4) + 63) & ~(size_t)63;
    int*    cnt   = (int*)ws;
    double* acc   = (double*)(ws + cntBytes);        // 32 B
    float*  stats = (float*)(ws + cntBytes + 32);    // 16 B
    int*    off   = (int*)(ws + cntBytes + 64);      // N+1
    int*    cur   = off + N + 1;                     // N+1
    int*    pos_t = cur + N + 1;                     // E
    int*    pos_s = pos_t + E;                       // E

    size_t head = cntBytes + 64 + sizeof(int) * ((size_t)2 * (N + 1) + 2 * (size_t)E);
    head = (head + 255) & ~(size_t)255;
    uint2* gbuf = (uint2*)(ws + head);
    size_t needed = head + (size_t)S * BB * sizeof(uint2);

    int eblocks = (E + 255) / 256;

    if (needed <= ws_size) {
        hipMemsetAsync(ws, 0, cntBytes + 32, stream);  // zero cnt + acc
        stats_count_kernel<<<256, 256, 0, stream>>>(ea, ei, E, acc, cnt);
        scan_kernel<<<1, 1024, 0, stream>>>(cnt, off, cur, N, acc, E, stats);
        fill_pos_kernel<<<eblocks, 256, 0, stream>>>(ei, E, cur, pos_t, pos_s);

        dim3 gridA(eblocks, BB);
        edge_mlp_store_kernel<<<gridA, 256, 0, stream>>>(
            x, ei, ea, wmean, wstd, W1, b1, W2, b2, W3, stats,
            pos_t, pos_s, gbuf, N, E, S);

        int pairs = N * BB;
        segment_sum_kernel<<<(pairs + 15) / 16, 256, 0, stream>>>(
            gbuf, off, b3, out, N, S);
    } else {
        hipMemsetAsync(ws, 0, cntBytes + 32, stream);
        hipMemsetAsync(d_out, 0, (size_t)out_size * sizeof(float), stream);
        stats_count_kernel<<<256, 256, 0, stream>>>(ea, ei, E, acc, cnt);
        scan_kernel<<<1, 1024, 0, stream>>>(cnt, off, cur, N, acc, E, stats);
        edge_atomic_kernel<<<eblocks, 256, 0, stream>>>(
            x, ei, ea, wmean, wstd, W1, b1, W2, b2, W3, stats, out, N, E);
        output_kernel<<<(out_size + 255) / 256, 256, 0, stream>>>(out, b3, out_size);
    }
}